// Round 1
// baseline (11917.641 us; speedup 1.0000x reference)
//
#include <hip/hip_runtime.h>
#include <cstdint>
#include <cstddef>

#define T_LEN 1024
#define CH    1024
#define NGATE 4096
#define LAT   128
#define NBLK  128   // cooperative LSTM blocks; each owns 8 hidden dims

// ---------------- ws layout (bytes) ----------------
// [0, 16 MiB)          : xg[T][4096]  precomputed input gates (+biases)
// [16 MiB, +8 KiB)     : hbuf[2][1024] double-buffered h broadcast
// [+8 KiB, +8 KiB)     : hcbuf[2048]   final concat(h, c)
// [next]               : ctrl[2] : {eos_idx, barrier_count}
#define WS_XG    0
#define WS_HBUF  (16777216)
#define WS_HCBUF (16777216 + 8192)
#define WS_CTRL  (16777216 + 8192 + 8192)

__device__ __forceinline__ float sigmf(float x) { return 1.0f / (1.0f + expf(-x)); }

// ---------------- kernel A: eos index + barrier init ----------------
__global__ __launch_bounds__(1024) void setup_k(const int* __restrict__ tok,
                                                int* __restrict__ ctrl) {
  __shared__ int red[1024];
  int tid = threadIdx.x;
  red[tid] = (tok[tid] == 1) ? tid : 0x7fffffff;
  __syncthreads();
  for (int s = 512; s > 0; s >>= 1) {
    if (tid < s) red[tid] = min(red[tid], red[tid + s]);
    __syncthreads();
  }
  if (tid == 0) {
    int e = red[0];
    ctrl[0] = (e == 0x7fffffff) ? 0 : e;   // argmax of all-false is 0
    ctrl[1] = 0;                           // barrier counter (ws is poisoned)
  }
}

// ---------------- kernel B: xg = gather(emb) @ W_ih^T + b_ih + b_hh ----------------
// C[t][r], tiles 128(t) x 128(r), 512 threads, 4x8 microtile, K-chunk 16.
__global__ __launch_bounds__(512) void xgemm_k(const int* __restrict__ tok,
                                               const float* __restrict__ emb,
                                               const float* __restrict__ Wih,
                                               const float* __restrict__ bih,
                                               const float* __restrict__ bhh,
                                               float* __restrict__ xg) {
  __shared__ float As[16 * 132];   // As[k][m] transposed, pad 132
  __shared__ float Bs[16 * 132];   // Bs[k][n]
  const int tid = threadIdx.x;
  const int r0 = blockIdx.x * 128;
  const int t0 = blockIdx.y * 128;
  const int tx = tid & 15, ty = tid >> 4;     // tx: r micro (8), ty: t micro (4)
  const int m0 = ty * 4, n0 = tx * 8;
  const int lrow = tid >> 2;                  // 0..127 loader row
  const int kq   = (tid & 3) * 4;             // 0,4,8,12

  float acc[4][8];
#pragma unroll
  for (int i = 0; i < 4; i++)
#pragma unroll
    for (int j = 0; j < 8; j++) acc[i][j] = 0.0f;

  const int tokv = tok[t0 + lrow];
  const float* arow = emb + (size_t)tokv * CH;
  const float* brow = Wih + (size_t)(r0 + lrow) * CH;

  for (int k0 = 0; k0 < CH; k0 += 16) {
    float4 a4 = *(const float4*)(arow + k0 + kq);
    float4 b4 = *(const float4*)(brow + k0 + kq);
    __syncthreads();   // previous iter's LDS reads complete
    As[(kq + 0) * 132 + lrow] = a4.x;
    As[(kq + 1) * 132 + lrow] = a4.y;
    As[(kq + 2) * 132 + lrow] = a4.z;
    As[(kq + 3) * 132 + lrow] = a4.w;
    Bs[(kq + 0) * 132 + lrow] = b4.x;
    Bs[(kq + 1) * 132 + lrow] = b4.y;
    Bs[(kq + 2) * 132 + lrow] = b4.z;
    Bs[(kq + 3) * 132 + lrow] = b4.w;
    __syncthreads();
#pragma unroll
    for (int kk = 0; kk < 16; kk++) {
      float4 av = *(const float4*)&As[kk * 132 + m0];
      float4 b0 = *(const float4*)&Bs[kk * 132 + n0];
      float4 b1 = *(const float4*)&Bs[kk * 132 + n0 + 4];
      float aa[4] = {av.x, av.y, av.z, av.w};
      float bb[8] = {b0.x, b0.y, b0.z, b0.w, b1.x, b1.y, b1.z, b1.w};
#pragma unroll
      for (int i = 0; i < 4; i++)
#pragma unroll
        for (int j = 0; j < 8; j++) acc[i][j] += aa[i] * bb[j];
    }
  }

  float4 bi0 = *(const float4*)(bih + r0 + n0);
  float4 bi1 = *(const float4*)(bih + r0 + n0 + 4);
  float4 bh0 = *(const float4*)(bhh + r0 + n0);
  float4 bh1 = *(const float4*)(bhh + r0 + n0 + 4);
  float badd[8] = {bi0.x + bh0.x, bi0.y + bh0.y, bi0.z + bh0.z, bi0.w + bh0.w,
                   bi1.x + bh1.x, bi1.y + bh1.y, bi1.z + bh1.z, bi1.w + bh1.w};
#pragma unroll
  for (int i = 0; i < 4; i++) {
    float4 o0 = {acc[i][0] + badd[0], acc[i][1] + badd[1],
                 acc[i][2] + badd[2], acc[i][3] + badd[3]};
    float4 o1 = {acc[i][4] + badd[4], acc[i][5] + badd[5],
                 acc[i][6] + badd[6], acc[i][7] + badd[7]};
    float* dst = xg + (size_t)(t0 + m0 + i) * NGATE + r0 + n0;
    *(float4*)(dst) = o0;
    *(float4*)(dst + 4) = o1;
  }
}

// ---------------- grid barrier (monotonic counter) ----------------
__device__ __forceinline__ void gbar(unsigned* cnt, unsigned target) {
  __syncthreads();
  if (threadIdx.x == 0) {
    __threadfence();
    atomicAdd(cnt, 1u);
    while (__hip_atomic_load(cnt, __ATOMIC_RELAXED, __HIP_MEMORY_SCOPE_AGENT) < target)
      __builtin_amdgcn_s_sleep(1);
    __threadfence();
  }
  __syncthreads();
}

// ---------------- kernel C: cooperative LSTM + projections ----------------
// 128 blocks x 1024 threads. Block b owns hidden dims [b*8, b*8+8) -> 32 gate rows.
// W_hh slice lives in registers: thread (g=tid>>5, s=tid&31) holds row
// r = (g>>3)*1024 + b*8 + (g&7), elements k = s + 32*i, i=0..31.
__global__ __launch_bounds__(1024) void lstm_k(const float* __restrict__ h0,
                                               const float* __restrict__ c0,
                                               const float* __restrict__ eps,
                                               const float* __restrict__ Whh,
                                               const float* __restrict__ Wm,
                                               const float* __restrict__ bm,
                                               const float* __restrict__ Wl,
                                               const float* __restrict__ bl,
                                               const float* __restrict__ xg,
                                               float* __restrict__ hbuf,
                                               float* __restrict__ hcbuf,
                                               int* __restrict__ ctrl,
                                               float* __restrict__ out) {
  __shared__ float hs[1024];
  __shared__ float gv[32];
  __shared__ float rs[32];

  const int tid = threadIdx.x;
  const int b = blockIdx.x;
  const int g = tid >> 5, s = tid & 31;
  const int q = g >> 3, jj = g & 7;
  const int r = q * 1024 + b * 8 + jj;

  const float* wrow = Whh + (size_t)r * CH;
  float w[32];
#pragma unroll
  for (int i = 0; i < 32; i++) w[i] = wrow[s + 32 * i];

  const int eos = ctrl[0];
  unsigned* cnt = (unsigned*)(ctrl + 1);

  float hreg = 0.0f, creg = 0.0f;
  if (tid < 8) { hreg = h0[b * 8 + tid]; creg = c0[b * 8 + tid]; }

  unsigned nbar = 0;
  for (int t = 0; t < eos; t++) {
    float xv = 0.0f;
    if (s == 0) xv = xg[(size_t)t * NGATE + r];   // prefetch early
    const float* hsrc = (t == 0) ? h0 : (hbuf + (t & 1) * 1024);
    hs[tid] = hsrc[tid];
    __syncthreads();

    float a0 = 0.0f, a1 = 0.0f;
#pragma unroll
    for (int i = 0; i < 32; i += 2) {
      a0 += w[i]     * hs[s + 32 * i];
      a1 += w[i + 1] * hs[s + 32 * (i + 1)];
    }
    float acc = a0 + a1;
    acc += __shfl_xor(acc, 16);
    acc += __shfl_xor(acc, 8);
    acc += __shfl_xor(acc, 4);
    acc += __shfl_xor(acc, 2);
    acc += __shfl_xor(acc, 1);
    if (s == 0) gv[g] = acc + xv;
    __syncthreads();

    if (tid < 8) {
      float iv = gv[tid], fv = gv[8 + tid], gg = gv[16 + tid], ov = gv[24 + tid];
      float cn = sigmf(fv) * creg + sigmf(iv) * tanhf(gg);
      float hn = sigmf(ov) * tanhf(cn);
      creg = cn; hreg = hn;
      hbuf[((t + 1) & 1) * 1024 + b * 8 + tid] = hn;
      __threadfence();
    }
    nbar++;
    gbar(cnt, nbar * NBLK);
  }

  // publish final h, c
  if (tid < 8) {
    hcbuf[b * 8 + tid] = hreg;
    hcbuf[1024 + b * 8 + tid] = creg;
    __threadfence();
  }
  nbar++;
  gbar(cnt, nbar * NBLK);

  // projections: block b computes mean[b], logv[b] (2048-dot each)
  float hc1 = hcbuf[tid];
  float hc2 = hcbuf[1024 + tid];
  float pm = Wm[(size_t)b * 2048 + tid] * hc1 + Wm[(size_t)b * 2048 + 1024 + tid] * hc2;
  float pl = Wl[(size_t)b * 2048 + tid] * hc1 + Wl[(size_t)b * 2048 + 1024 + tid] * hc2;
#pragma unroll
  for (int o = 32; o > 0; o >>= 1) {
    pm += __shfl_down(pm, o);
    pl += __shfl_down(pl, o);
  }
  const int wv = tid >> 6, ln = tid & 63;
  if (ln == 0) { rs[wv] = pm; rs[16 + wv] = pl; }
  __syncthreads();
  if (tid == 0) {
    float m = 0.0f, l = 0.0f;
    for (int i = 0; i < 16; i++) { m += rs[i]; l += rs[16 + i]; }
    m += bm[b];
    l += bl[b];
    float z = eps[b] * expf(0.5f * l) + m;
    out[b] = z;
    out[LAT + b] = m;
    out[2 * LAT + b] = l;
  }
}

extern "C" void kernel_launch(void* const* d_in, const int* in_sizes, int n_in,
                              void* d_out, int out_size, void* d_ws, size_t ws_size,
                              hipStream_t stream) {
  const int*   tok = (const int*)d_in[0];
  const float* h0  = (const float*)d_in[1];
  const float* c0  = (const float*)d_in[2];
  const float* eps = (const float*)d_in[3];
  const float* emb = (const float*)d_in[4];
  const float* Wih = (const float*)d_in[5];
  const float* Whh = (const float*)d_in[6];
  const float* bih = (const float*)d_in[7];
  const float* bhh = (const float*)d_in[8];
  const float* Wm  = (const float*)d_in[9];
  const float* bm  = (const float*)d_in[10];
  const float* Wl  = (const float*)d_in[11];
  const float* bl  = (const float*)d_in[12];
  float* out = (float*)d_out;

  char* ws = (char*)d_ws;
  float* xg    = (float*)(ws + WS_XG);
  float* hbuf  = (float*)(ws + WS_HBUF);
  float* hcbuf = (float*)(ws + WS_HCBUF);
  int*   ctrl  = (int*)(ws + WS_CTRL);

  setup_k<<<1, 1024, 0, stream>>>(tok, ctrl);
  xgemm_k<<<dim3(NGATE / 128, T_LEN / 128), 512, 0, stream>>>(tok, emb, Wih, bih, bhh, xg);

  void* args[] = {(void*)&h0, (void*)&c0, (void*)&eps, (void*)&Whh,
                  (void*)&Wm, (void*)&bm, (void*)&Wl, (void*)&bl,
                  (void*)&xg, (void*)&hbuf, (void*)&hcbuf, (void*)&ctrl, (void*)&out};
  hipLaunchCooperativeKernel((void*)lstm_k, dim3(NBLK), dim3(1024), args, 0, stream);
}

// Round 2
// 2461.596 us; speedup vs baseline: 4.8414x; 4.8414x over previous
//
#include <hip/hip_runtime.h>
#include <cstdint>
#include <cstddef>

#define T_LEN 1024
#define CH    1024
#define NGATE 4096
#define LAT   128
#define NBLK  128   // cooperative LSTM blocks; each owns 8 hidden dims

// ---------------- ws layout (bytes) ----------------
// [0, 16 MiB)   : xg[T][4096]        precomputed input gates (+biases)
// [+0 KiB]      : hbuf64[2][1024]    tagged h broadcast (u64: tag<<32 | bits)
// [+16 KiB]     : hfin64[1024]       tagged final h (tag==1)
// [+24 KiB]     : cfin64[1024]       tagged final c (tag==1)
// [+32 KiB]     : ctrl[1] : {eos_idx}
#define WS_XG    0
#define WS_HBUF  (16777216)
#define WS_HFIN  (16777216 + 16384)
#define WS_CFIN  (16777216 + 24576)
#define WS_CTRL  (16777216 + 32768)

__device__ __forceinline__ float sigmf(float x) { return 1.0f / (1.0f + expf(-x)); }

// ---------------- kernel A: eos index ----------------
__global__ __launch_bounds__(1024) void setup_k(const int* __restrict__ tok,
                                                int* __restrict__ ctrl) {
  __shared__ int red[1024];
  int tid = threadIdx.x;
  red[tid] = (tok[tid] == 1) ? tid : 0x7fffffff;
  __syncthreads();
  for (int s = 512; s > 0; s >>= 1) {
    if (tid < s) red[tid] = min(red[tid], red[tid + s]);
    __syncthreads();
  }
  if (tid == 0) {
    int e = red[0];
    ctrl[0] = (e == 0x7fffffff) ? 0 : e;   // argmax of all-false is 0
  }
}

// ---------------- kernel B: xg = gather(emb) @ W_ih^T + b_ih + b_hh ----------------
// C[t][r], tiles 128(t) x 128(r), 512 threads, 4x8 microtile, K-chunk 16.
__global__ __launch_bounds__(512) void xgemm_k(const int* __restrict__ tok,
                                               const float* __restrict__ emb,
                                               const float* __restrict__ Wih,
                                               const float* __restrict__ bih,
                                               const float* __restrict__ bhh,
                                               float* __restrict__ xg) {
  __shared__ float As[16 * 132];   // As[k][m] transposed, pad 132
  __shared__ float Bs[16 * 132];   // Bs[k][n]
  const int tid = threadIdx.x;
  const int r0 = blockIdx.x * 128;
  const int t0 = blockIdx.y * 128;
  const int tx = tid & 15, ty = tid >> 4;     // tx: r micro (8), ty: t micro (4)
  const int m0 = ty * 4, n0 = tx * 8;
  const int lrow = tid >> 2;                  // 0..127 loader row
  const int kq   = (tid & 3) * 4;             // 0,4,8,12

  float acc[4][8];
#pragma unroll
  for (int i = 0; i < 4; i++)
#pragma unroll
    for (int j = 0; j < 8; j++) acc[i][j] = 0.0f;

  const int tokv = tok[t0 + lrow];
  const float* arow = emb + (size_t)tokv * CH;
  const float* brow = Wih + (size_t)(r0 + lrow) * CH;

  for (int k0 = 0; k0 < CH; k0 += 16) {
    float4 a4 = *(const float4*)(arow + k0 + kq);
    float4 b4 = *(const float4*)(brow + k0 + kq);
    __syncthreads();   // previous iter's LDS reads complete
    As[(kq + 0) * 132 + lrow] = a4.x;
    As[(kq + 1) * 132 + lrow] = a4.y;
    As[(kq + 2) * 132 + lrow] = a4.z;
    As[(kq + 3) * 132 + lrow] = a4.w;
    Bs[(kq + 0) * 132 + lrow] = b4.x;
    Bs[(kq + 1) * 132 + lrow] = b4.y;
    Bs[(kq + 2) * 132 + lrow] = b4.z;
    Bs[(kq + 3) * 132 + lrow] = b4.w;
    __syncthreads();
#pragma unroll
    for (int kk = 0; kk < 16; kk++) {
      float4 av = *(const float4*)&As[kk * 132 + m0];
      float4 b0 = *(const float4*)&Bs[kk * 132 + n0];
      float4 b1 = *(const float4*)&Bs[kk * 132 + n0 + 4];
      float aa[4] = {av.x, av.y, av.z, av.w};
      float bb[8] = {b0.x, b0.y, b0.z, b0.w, b1.x, b1.y, b1.z, b1.w};
#pragma unroll
      for (int i = 0; i < 4; i++)
#pragma unroll
        for (int j = 0; j < 8; j++) acc[i][j] += aa[i] * bb[j];
    }
  }

  float4 bi0 = *(const float4*)(bih + r0 + n0);
  float4 bi1 = *(const float4*)(bih + r0 + n0 + 4);
  float4 bh0 = *(const float4*)(bhh + r0 + n0);
  float4 bh1 = *(const float4*)(bhh + r0 + n0 + 4);
  float badd[8] = {bi0.x + bh0.x, bi0.y + bh0.y, bi0.z + bh0.z, bi0.w + bh0.w,
                   bi1.x + bh1.x, bi1.y + bh1.y, bi1.z + bh1.z, bi1.w + bh1.w};
#pragma unroll
  for (int i = 0; i < 4; i++) {
    float4 o0 = {acc[i][0] + badd[0], acc[i][1] + badd[1],
                 acc[i][2] + badd[2], acc[i][3] + badd[3]};
    float4 o1 = {acc[i][4] + badd[4], acc[i][5] + badd[5],
                 acc[i][6] + badd[6], acc[i][7] + badd[7]};
    float* dst = xg + (size_t)(t0 + m0 + i) * NGATE + r0 + n0;
    *(float4*)(dst) = o0;
    *(float4*)(dst + 4) = o1;
  }
}

// ---------------- kernel C: cooperative LSTM + projections ----------------
// 128 blocks x 1024 threads. Block b owns hidden dims [b*8, b*8+8) -> 32 gate rows.
// W_hh slice lives in registers: thread (g=tid>>5, s=tid&31) holds row
// r = (g>>3)*1024 + b*8 + (g&7), elements k = s + 32*i, i=0..31.
//
// Cross-block h exchange: fence-free tagged 64-bit relaxed device-scope atomics.
// Payload = (tag<<32)|float_bits; tag t+1 published into slot (t+1)&1.
// D=2 double-buffer is race-free: publishing tag t+2 requires having consumed
// ALL tags t+1, which implies every block finished reading slot t&1.
__global__ __launch_bounds__(1024) void lstm_k(const float* __restrict__ h0,
                                               const float* __restrict__ c0,
                                               const float* __restrict__ eps,
                                               const float* __restrict__ Whh,
                                               const float* __restrict__ Wm,
                                               const float* __restrict__ bm,
                                               const float* __restrict__ Wl,
                                               const float* __restrict__ bl,
                                               const float* __restrict__ xg,
                                               unsigned long long* __restrict__ hbuf64,
                                               unsigned long long* __restrict__ hfin64,
                                               unsigned long long* __restrict__ cfin64,
                                               const int* __restrict__ ctrl,
                                               float* __restrict__ out) {
  __shared__ float hs[1024];
  __shared__ float hcs[2048];
  __shared__ float gv[32];
  __shared__ float rs[32];

  const int tid = threadIdx.x;
  const int b = blockIdx.x;
  const int g = tid >> 5, s = tid & 31;
  const int q = g >> 3, jj = g & 7;
  const int r = q * 1024 + b * 8 + jj;

  const float* wrow = Whh + (size_t)r * CH;
  float w[32];
#pragma unroll
  for (int i = 0; i < 32; i++) w[i] = wrow[s + 32 * i];

  const int eos = ctrl[0];

  float hreg = 0.0f, creg = 0.0f;
  if (tid < 8) { hreg = h0[b * 8 + tid]; creg = c0[b * 8 + tid]; }

  for (int t = 0; t < eos; t++) {
    float xv = 0.0f;
    if (s == 0) xv = xg[(size_t)t * NGATE + r];   // issue early, overlaps poll

    if (t == 0) {
      hs[tid] = h0[tid];
    } else {
      const unsigned want = (unsigned)t;
      const unsigned long long* src = hbuf64 + (size_t)(t & 1) * 1024 + tid;
      unsigned long long v;
      do {
        v = __hip_atomic_load(src, __ATOMIC_RELAXED, __HIP_MEMORY_SCOPE_AGENT);
      } while ((unsigned)(v >> 32) != want);
      hs[tid] = __uint_as_float((unsigned)(v & 0xffffffffu));
    }
    __syncthreads();

    float a0 = 0.0f, a1 = 0.0f;
#pragma unroll
    for (int i = 0; i < 32; i += 2) {
      a0 += w[i]     * hs[s + 32 * i];
      a1 += w[i + 1] * hs[s + 32 * (i + 1)];
    }
    float acc = a0 + a1;
    acc += __shfl_xor(acc, 16);
    acc += __shfl_xor(acc, 8);
    acc += __shfl_xor(acc, 4);
    acc += __shfl_xor(acc, 2);
    acc += __shfl_xor(acc, 1);
    if (s == 0) gv[g] = acc + xv;
    __syncthreads();   // also retires all hs reads before next iter's writes

    if (tid < 8) {
      float iv = gv[tid], fv = gv[8 + tid], gg = gv[16 + tid], ov = gv[24 + tid];
      float cn = sigmf(fv) * creg + sigmf(iv) * tanhf(gg);
      float hn = sigmf(ov) * tanhf(cn);
      creg = cn; hreg = hn;
      unsigned long long pv = ((unsigned long long)(unsigned)(t + 1) << 32) |
                              (unsigned long long)__float_as_uint(hn);
      __hip_atomic_store(&hbuf64[(size_t)((t + 1) & 1) * 1024 + b * 8 + tid], pv,
                         __ATOMIC_RELAXED, __HIP_MEMORY_SCOPE_AGENT);
    }
  }

  // publish final h, c into dedicated tagged buffers (tag == 1; poison never matches)
  if (tid < 8) {
    unsigned long long ph = (1ull << 32) | (unsigned long long)__float_as_uint(hreg);
    unsigned long long pc = (1ull << 32) | (unsigned long long)__float_as_uint(creg);
    __hip_atomic_store(&hfin64[b * 8 + tid], ph, __ATOMIC_RELAXED, __HIP_MEMORY_SCOPE_AGENT);
    __hip_atomic_store(&cfin64[b * 8 + tid], pc, __ATOMIC_RELAXED, __HIP_MEMORY_SCOPE_AGENT);
  }

  // gather full hc = concat(h, c)
  {
    unsigned long long vh, vc;
    do {
      vh = __hip_atomic_load(&hfin64[tid], __ATOMIC_RELAXED, __HIP_MEMORY_SCOPE_AGENT);
    } while ((unsigned)(vh >> 32) != 1u);
    do {
      vc = __hip_atomic_load(&cfin64[tid], __ATOMIC_RELAXED, __HIP_MEMORY_SCOPE_AGENT);
    } while ((unsigned)(vc >> 32) != 1u);
    hcs[tid] = __uint_as_float((unsigned)(vh & 0xffffffffu));
    hcs[1024 + tid] = __uint_as_float((unsigned)(vc & 0xffffffffu));
  }
  __syncthreads();

  // projections: block b computes mean[b], logv[b] (2048-dot each)
  float hc1 = hcs[tid];
  float hc2 = hcs[1024 + tid];
  float pm = Wm[(size_t)b * 2048 + tid] * hc1 + Wm[(size_t)b * 2048 + 1024 + tid] * hc2;
  float pl = Wl[(size_t)b * 2048 + tid] * hc1 + Wl[(size_t)b * 2048 + 1024 + tid] * hc2;
#pragma unroll
  for (int o = 32; o > 0; o >>= 1) {
    pm += __shfl_down(pm, o);
    pl += __shfl_down(pl, o);
  }
  const int wv = tid >> 6, ln = tid & 63;
  if (ln == 0) { rs[wv] = pm; rs[16 + wv] = pl; }
  __syncthreads();
  if (tid == 0) {
    float m = 0.0f, l = 0.0f;
    for (int i = 0; i < 16; i++) { m += rs[i]; l += rs[16 + i]; }
    m += bm[b];
    l += bl[b];
    float z = eps[b] * expf(0.5f * l) + m;
    out[b] = z;
    out[LAT + b] = m;
    out[2 * LAT + b] = l;
  }
}

extern "C" void kernel_launch(void* const* d_in, const int* in_sizes, int n_in,
                              void* d_out, int out_size, void* d_ws, size_t ws_size,
                              hipStream_t stream) {
  const int*   tok = (const int*)d_in[0];
  const float* h0  = (const float*)d_in[1];
  const float* c0  = (const float*)d_in[2];
  const float* eps = (const float*)d_in[3];
  const float* emb = (const float*)d_in[4];
  const float* Wih = (const float*)d_in[5];
  const float* Whh = (const float*)d_in[6];
  const float* bih = (const float*)d_in[7];
  const float* bhh = (const float*)d_in[8];
  const float* Wm  = (const float*)d_in[9];
  const float* bm  = (const float*)d_in[10];
  const float* Wl  = (const float*)d_in[11];
  const float* bl  = (const float*)d_in[12];
  float* out = (float*)d_out;

  char* ws = (char*)d_ws;
  float* xg = (float*)(ws + WS_XG);
  unsigned long long* hbuf64 = (unsigned long long*)(ws + WS_HBUF);
  unsigned long long* hfin64 = (unsigned long long*)(ws + WS_HFIN);
  unsigned long long* cfin64 = (unsigned long long*)(ws + WS_CFIN);
  int* ctrl = (int*)(ws + WS_CTRL);

  setup_k<<<1, 1024, 0, stream>>>(tok, ctrl);
  xgemm_k<<<dim3(NGATE / 128, T_LEN / 128), 512, 0, stream>>>(tok, emb, Wih, bih, bhh, xg);

  void* args[] = {(void*)&h0, (void*)&c0, (void*)&eps, (void*)&Whh,
                  (void*)&Wm, (void*)&bm, (void*)&Wl, (void*)&bl,
                  (void*)&xg, (void*)&hbuf64, (void*)&hfin64, (void*)&cfin64,
                  (void*)&ctrl, (void*)&out};
  hipLaunchCooperativeKernel((void*)lstm_k, dim3(NBLK), dim3(1024), args, 0, stream);
}